// Round 4
// baseline (1037.628 us; speedup 1.0000x reference)
//
#include <hip/hip_runtime.h>

// Diffeomorphic transform (scaling & squaring), 7 steps.
// flow: [1, 3, 192, 192, 192] fp32, c=0 -> z disp, c=1 -> y, c=2 -> x.
// out = f + trilinear_sample(f, voxel + f*(size-1)/2), border clamp,
// align_corners=True (identity grid unnormalizes exactly to voxel index).
//
// R2: XCD swizzle (kept). R3: channel-interleaved intermediates (kept).
// R4: 12B vector gathers. R3 counters showed HBM 3.4%, VALU 15%, occ 84% ->
// bound on divergent-address throughput (24 scalar gather loads/voxel).
// Interleaved corners are 12 contiguous bytes: one dwordx3 per corner -> 8
// gather instructions per voxel instead of 24.

constexpr int DD = 192, HH = 192, WW = 192;
constexpr int NN = DD * HH * WW;
constexpr int NB = NN / 256;      // 27648 blocks
constexpr int NXCD = 8;
constexpr int CHUNK = NB / NXCD;  // 3456 (exact -> bijective swizzle)

struct F3 { float x, y, z; };     // size 12, align 4 -> global_load_dwordx3

// SES/SCS: source element/channel stride; DES/DCS: dest. Planar: (1, NN).
// Interleaved: (3, 1).
template <int SES, int SCS, int DES, int DCS>
__global__ __launch_bounds__(256) void diffeo_step(
    const float* __restrict__ src, float* __restrict__ dst, float scale)
{
    int bid = blockIdx.x;
    int swz = (bid & (NXCD - 1)) * CHUNK + (bid >> 3);
    int idx = swz * 256 + threadIdx.x;

    int w = idx % WW;
    int t = idx / WW;
    int h = t % HH;
    int d = t / HH;

    float f0, f1, f2;
    if constexpr (SES == 3) {
        F3 own = *reinterpret_cast<const F3*>(src + idx * 3);
        f0 = own.x * scale; f1 = own.y * scale; f2 = own.z * scale;
    } else {
        f0 = src[idx]          * scale;
        f1 = src[idx + NN]     * scale;
        f2 = src[idx + 2 * NN] * scale;
    }

    float x = fminf(fmaxf((float)w + f2 * (0.5f * (WW - 1)), 0.0f), (float)(WW - 1));
    float y = fminf(fmaxf((float)h + f1 * (0.5f * (HH - 1)), 0.0f), (float)(HH - 1));
    float z = fminf(fmaxf((float)d + f0 * (0.5f * (DD - 1)), 0.0f), (float)(DD - 1));

    int x0 = (int)x;  float wx = x - (float)x0;
    int y0 = (int)y;  float wy = y - (float)y0;
    int z0 = (int)z;  float wz = z - (float)z0;
    int x1 = min(x0 + 1, WW - 1);
    int y1 = min(y0 + 1, HH - 1);
    int z1 = min(z0 + 1, DD - 1);

    float ox = 1.0f - wx, oy = 1.0f - wy, oz = 1.0f - wz;
    float w000 = ox * oy * oz;
    float w001 = wx * oy * oz;
    float w010 = ox * wy * oz;
    float w011 = wx * wy * oz;
    float w100 = ox * oy * wz;
    float w101 = wx * oy * wz;
    float w110 = ox * wy * wz;
    float w111 = wx * wy * wz;

    int i000 = (z0 * HH + y0) * WW + x0;
    int i001 = (z0 * HH + y0) * WW + x1;
    int i010 = (z0 * HH + y1) * WW + x0;
    int i011 = (z0 * HH + y1) * WW + x1;
    int i100 = (z1 * HH + y0) * WW + x0;
    int i101 = (z1 * HH + y0) * WW + x1;
    int i110 = (z1 * HH + y1) * WW + x0;
    int i111 = (z1 * HH + y1) * WW + x1;

    float v0, v1, v2;
    if constexpr (SES == 3) {
        const F3* s3 = reinterpret_cast<const F3*>(src);
        F3 c000 = s3[i000], c001 = s3[i001], c010 = s3[i010], c011 = s3[i011];
        F3 c100 = s3[i100], c101 = s3[i101], c110 = s3[i110], c111 = s3[i111];
        v0 = w000 * c000.x + w001 * c001.x + w010 * c010.x + w011 * c011.x
           + w100 * c100.x + w101 * c101.x + w110 * c110.x + w111 * c111.x;
        v1 = w000 * c000.y + w001 * c001.y + w010 * c010.y + w011 * c011.y
           + w100 * c100.y + w101 * c101.y + w110 * c110.y + w111 * c111.y;
        v2 = w000 * c000.z + w001 * c001.z + w010 * c010.z + w011 * c011.z
           + w100 * c100.z + w101 * c101.z + w110 * c110.z + w111 * c111.z;
    } else {
        float acc[3];
#pragma unroll
        for (int c = 0; c < 3; ++c) {
            const float* s = src + c * SCS;
            acc[c] =
                w000 * s[i000] + w001 * s[i001] +
                w010 * s[i010] + w011 * s[i011] +
                w100 * s[i100] + w101 * s[i101] +
                w110 * s[i110] + w111 * s[i111];
        }
        v0 = acc[0]; v1 = acc[1]; v2 = acc[2];
    }

    if constexpr (DES == 3) {
        F3 o = { f0 + scale * v0, f1 + scale * v1, f2 + scale * v2 };
        *reinterpret_cast<F3*>(dst + idx * 3) = o;
    } else {
        dst[idx]          = f0 + scale * v0;
        dst[idx + NN]     = f1 + scale * v1;
        dst[idx + 2 * NN] = f2 + scale * v2;
    }
}

extern "C" void kernel_launch(void* const* d_in, const int* in_sizes, int n_in,
                              void* d_out, int out_size, void* d_ws, size_t ws_size,
                              hipStream_t stream) {
    const float* in = (const float*)d_in[0];
    float* out = (float*)d_out;
    float* ws  = (float*)d_ws;

    const float inv = 1.0f / 128.0f;  // 2^-TIME_STEP, TIME_STEP=7

    // Layouts: input planar; intermediates interleaved; final output planar.
    diffeo_step<1, NN, 3, 1><<<NB, 256, 0, stream>>>(in,  out, inv);   // it1
    diffeo_step<3, 1,  3, 1><<<NB, 256, 0, stream>>>(out, ws,  1.0f);  // it2
    diffeo_step<3, 1,  3, 1><<<NB, 256, 0, stream>>>(ws,  out, 1.0f);  // it3
    diffeo_step<3, 1,  3, 1><<<NB, 256, 0, stream>>>(out, ws,  1.0f);  // it4
    diffeo_step<3, 1,  3, 1><<<NB, 256, 0, stream>>>(ws,  out, 1.0f);  // it5
    diffeo_step<3, 1,  3, 1><<<NB, 256, 0, stream>>>(out, ws,  1.0f);  // it6
    diffeo_step<3, 1,  1, NN><<<NB, 256, 0, stream>>>(ws,  out, 1.0f); // it7
}